// Round 5
// baseline (204.462 us; speedup 1.0000x reference)
//
#include <hip/hip_runtime.h>
#include <math.h>

#define N_NODES 16384
#define D_MODEL 256
#define H_HEADS 4
#define C_CH 256
#define E_EDGES 65536
#define ETOT (E_EDGES + N_NODES)
#define HC 1024
#define MAXDEG 64

typedef __bf16 bf16x8 __attribute__((ext_vector_type(8)));
typedef __bf16 bf16x4 __attribute__((ext_vector_type(4)));
typedef float f32x4 __attribute__((ext_vector_type(4)));

__device__ __forceinline__ __bf16 f2bf(float f) { return (__bf16)f; }
__device__ __forceinline__ float bf2f(__bf16 b) { return (float)b; }

// ==== K1: everything that only needs raw inputs, one fat dispatch ====
// b==0        : t = Wg^T@att (8 vecs) -> u2 = t@W1, c0 = t.b1   (two-phase, LDS)
// b in [1,257): Wz[og,h,:] = (sum_c W2[og,c] Wg[h,c,:]) @ W1  (self-contained,
//               V intermediate lives in 4KB LDS; also bias_z contributions)
// b in [257,577): padded-CSR scatter (no deg-hist, no scan: stride-64 rows)
// b >= 577    : LayerNorm -> x_ln bf16
// Skinny branches are FIRST so they start immediately and hide under LN.
__global__ __launch_bounds__(256) void fused_prep_ln(
    const float* __restrict__ Wg, const float* __restrict__ att_src,
    const float* __restrict__ att_dst, const float* __restrict__ W1,
    const float* __restrict__ b1, const float* __restrict__ W2,
    const float* __restrict__ bg, const float* __restrict__ b2,
    const int* __restrict__ ei, const float* __restrict__ in,
    const float* __restrict__ gamma, const float* __restrict__ beta,
    __bf16* __restrict__ x_ln, __bf16* __restrict__ Wz,
    float* __restrict__ bias_z, float* __restrict__ u2,
    float* __restrict__ c0, int* __restrict__ cnt, int* __restrict__ csr)
{
    int b = blockIdx.x;
    int tid = threadIdx.x;

    if (b >= 577) {
        // ---------------- LayerNorm ----------------
        int wave = tid >> 6, lane = tid & 63;
        int row = (b - 577) * 4 + wave;
        float4 v = ((const float4*)(in + (size_t)row * D_MODEL))[lane];
        float s  = v.x + v.y + v.z + v.w;
        float sq = v.x*v.x + v.y*v.y + v.z*v.z + v.w*v.w;
        for (int off = 32; off; off >>= 1) {
            s  += __shfl_xor(s,  off);
            sq += __shfl_xor(sq, off);
        }
        float mean = s * (1.0f / D_MODEL);
        float var  = sq * (1.0f / D_MODEL) - mean * mean;
        float inv  = rsqrtf(var + 1e-6f);
        float4 g  = ((const float4*)gamma)[lane];
        float4 bb = ((const float4*)beta)[lane];
        bf16x4 o;
        o[0] = f2bf((v.x - mean) * inv * g.x + bb.x);
        o[1] = f2bf((v.y - mean) * inv * g.y + bb.y);
        o[2] = f2bf((v.z - mean) * inv * g.z + bb.z);
        o[3] = f2bf((v.w - mean) * inv * g.w + bb.w);
        *(bf16x4*)(x_ln + (size_t)row * D_MODEL + lane * 4) = o;
        return;
    }

    if (b == 0) {
        // ---------------- t -> u2, c0 (single block, two-phase) ----------------
        __shared__ float tsh[8][256];
        float tv[8] = {0.f, 0.f, 0.f, 0.f, 0.f, 0.f, 0.f, 0.f};
        #pragma unroll
        for (int h = 0; h < 4; ++h) {
            const float* as = att_src + h * 256;
            const float* ad = att_dst + h * 256;
            const float* wcol = Wg + ((size_t)h * 256) * 256 + tid;
            #pragma unroll 4
            for (int c = 0; c < 256; ++c) {
                float wv = wcol[(size_t)c * 256];
                tv[h]     = fmaf(wv, as[c], tv[h]);
                tv[h + 4] = fmaf(wv, ad[c], tv[h + 4]);
            }
        }
        #pragma unroll
        for (int v = 0; v < 8; ++v) tsh[v][tid] = tv[v];
        __syncthreads();
        float u[8] = {0.f, 0.f, 0.f, 0.f, 0.f, 0.f, 0.f, 0.f};
        #pragma unroll 4
        for (int k = 0; k < 256; ++k) {
            float w1v = W1[(size_t)k * 256 + tid];
            #pragma unroll
            for (int v = 0; v < 8; ++v) u[v] = fmaf(tsh[v][k], w1v, u[v]);
        }
        #pragma unroll
        for (int v = 0; v < 8; ++v) u2[v * 256 + tid] = u[v];
        if (tid < 8) {
            float s = 0.f;
            for (int k = 0; k < 256; ++k) s = fmaf(tsh[tid][k], b1[k], s);
            c0[tid] = s;
        }
        return;
    }

    if (b < 257) {
        // ---------------- Wz compose (self-contained) ----------------
        int bb = b - 1;
        int og = (bb & 63) * 4, h = bb >> 6;
        int lane = tid & 63, wid = tid >> 6;
        __shared__ float vsh[4][256];
        __shared__ float red[4][4];

        const float* w2r = W2 + (size_t)og * 256;
        const float* wgp = Wg + ((size_t)h * 256) * 256 + tid;
        float a0 = 0.f, a1 = 0.f, a2 = 0.f, a3 = 0.f;
        #pragma unroll 4
        for (int c = 0; c < 256; ++c) {
            float wv = wgp[(size_t)c * 256];
            a0 = fmaf(w2r[c],       wv, a0);
            a1 = fmaf(w2r[256 + c], wv, a1);
            a2 = fmaf(w2r[512 + c], wv, a2);
            a3 = fmaf(w2r[768 + c], wv, a3);
        }
        vsh[0][tid] = a0; vsh[1][tid] = a1; vsh[2][tid] = a2; vsh[3][tid] = a3;
        __syncthreads();

        float o0 = 0.f, o1 = 0.f, o2 = 0.f, o3 = 0.f;
        #pragma unroll 4
        for (int k = 0; k < 256; ++k) {
            float w1v = W1[(size_t)k * 256 + tid];
            o0 = fmaf(vsh[0][k], w1v, o0);
            o1 = fmaf(vsh[1][k], w1v, o1);
            o2 = fmaf(vsh[2][k], w1v, o2);
            o3 = fmaf(vsh[3][k], w1v, o3);
        }
        size_t base = (size_t)og * 1024 + h * 256 + tid;
        Wz[base]        = f2bf(o0);
        Wz[base + 1024] = f2bf(o1);
        Wz[base + 2048] = f2bf(o2);
        Wz[base + 3072] = f2bf(o3);

        float b1v = b1[tid];
        #pragma unroll
        for (int j = 0; j < 4; ++j) {
            float p = vsh[j][tid] * b1v;
            for (int s = 32; s; s >>= 1) p += __shfl_xor(p, s);
            if (lane == 0) red[j][wid] = p;
        }
        __syncthreads();
        if (tid < 4) {
            float s = red[tid][0] + red[tid][1] + red[tid][2] + red[tid][3];
            atomicAdd(&bias_z[og + tid], 0.25f * s);
        }
        if (h == 0) {
            __syncthreads();
            float bgv = bg[tid];
            #pragma unroll
            for (int j = 0; j < 4; ++j) {
                float q = W2[(size_t)(og + j) * 256 + tid] * bgv;
                for (int s = 32; s; s >>= 1) q += __shfl_xor(q, s);
                if (lane == 0) red[j][wid] = q;
            }
            __syncthreads();
            if (tid < 4) {
                float s = red[tid][0] + red[tid][1] + red[tid][2] + red[tid][3];
                atomicAdd(&bias_z[og + tid], s + b2[og + tid]);
            }
        }
        return;
    }

    // ---------------- padded-CSR scatter ----------------
    {
        int e = (b - 257) * 256 + tid;
        int src, dst;
        if (e < E_EDGES) { src = ei[e]; dst = ei[E_EDGES + e]; }
        else             { src = dst = e - E_EDGES; }
        int pos = atomicAdd(cnt + dst, 1);
        csr[(size_t)dst * MAXDEG + pos] = src;
    }
}

// ==== K2: logits (per-node dots with u2, staged in LDS) ====
__global__ __launch_bounds__(256) void logits_k(
    const __bf16* __restrict__ x_ln, const float* __restrict__ u2,
    const float* __restrict__ c0, float* __restrict__ a_src,
    float* __restrict__ a_dst)
{
    int b = blockIdx.x;
    int tid = threadIdx.x;
    __shared__ float u2s[8][256];
    __shared__ float c0s[8];
    #pragma unroll
    for (int k = 0; k < 8; ++k) u2s[k][tid] = u2[k * 256 + tid];
    if (tid < 8) c0s[tid] = c0[tid];
    __syncthreads();

    int wave = tid >> 6, lane = tid & 63;
    int n = b * 4 + wave;
    int v = lane >> 3, p = lane & 7;
    const __bf16* xp = x_ln + (size_t)n * D_MODEL + p * 32;
    const float*  up = &u2s[v][p * 32];
    float acc = 0.f;
    #pragma unroll
    for (int ti = 0; ti < 4; ++ti) {
        bf16x8 x = *(const bf16x8*)(xp + ti * 8);
        #pragma unroll
        for (int j = 0; j < 8; ++j)
            acc = fmaf(bf2f(x[j]), up[ti * 8 + j], acc);
    }
    acc += __shfl_xor(acc, 1);
    acc += __shfl_xor(acc, 2);
    acc += __shfl_xor(acc, 4);
    if (p == 0) {
        float o = acc + c0s[v];
        if (v < 4) a_src[n * H_HEADS + v] = o;
        else       a_dst[n * H_HEADS + (v - 4)] = o;
    }
}

// ==== K3: fused softmax + aggregation ====
// Padded CSR: indices for the whole row loaded by one coalesced lane-load,
// distributed via __shfl — removes the index-load from every gather chain.
// unroll-4: four independent gather chains in flight.
__global__ __launch_bounds__(256) void gat_fused(
    const __bf16* __restrict__ x_ln, const float* __restrict__ a_src,
    const float* __restrict__ a_dst, const int* __restrict__ cnt,
    const int* __restrict__ csr, __bf16* __restrict__ agg)
{
    int wave = threadIdx.x >> 6, lane = threadIdx.x & 63;
    int i = blockIdx.x * 4 + wave;
    int deg = cnt[i];
    int sidx = csr[(size_t)i * MAXDEG + lane];   // coalesced; garbage past deg
    float4 ad = *(const float4*)(a_dst + i * H_HEADS);

    float acc[4][4] = {};
    float sm0 = 0.f, sm1 = 0.f, sm2 = 0.f, sm3 = 0.f;

    int e = 0;
    for (; e + 4 <= deg; e += 4) {
        int s0 = __shfl(sidx, e);
        int s1 = __shfl(sidx, e + 1);
        int s2 = __shfl(sidx, e + 2);
        int s3 = __shfl(sidx, e + 3);
        float4 A0 = *(const float4*)(a_src + s0 * H_HEADS);
        float4 A1 = *(const float4*)(a_src + s1 * H_HEADS);
        float4 A2 = *(const float4*)(a_src + s2 * H_HEADS);
        float4 A3 = *(const float4*)(a_src + s3 * H_HEADS);
        bf16x4 X0 = *(const bf16x4*)(x_ln + (size_t)s0 * D_MODEL + lane * 4);
        bf16x4 X1 = *(const bf16x4*)(x_ln + (size_t)s1 * D_MODEL + lane * 4);
        bf16x4 X2 = *(const bf16x4*)(x_ln + (size_t)s2 * D_MODEL + lane * 4);
        bf16x4 X3 = *(const bf16x4*)(x_ln + (size_t)s3 * D_MODEL + lane * 4);

        float l[4][4] = {
            {A0.x + ad.x, A0.y + ad.y, A0.z + ad.z, A0.w + ad.w},
            {A1.x + ad.x, A1.y + ad.y, A1.z + ad.z, A1.w + ad.w},
            {A2.x + ad.x, A2.y + ad.y, A2.z + ad.z, A2.w + ad.w},
            {A3.x + ad.x, A3.y + ad.y, A3.z + ad.z, A3.w + ad.w}};
        float wgt[4][4];
        #pragma unroll
        for (int q = 0; q < 4; ++q)
            #pragma unroll
            for (int h = 0; h < 4; ++h) {
                float lv = l[q][h];
                lv = (lv > 0.f) ? lv : 0.2f * lv;
                wgt[q][h] = __expf(lv);
            }
        sm0 += wgt[0][0] + wgt[1][0] + wgt[2][0] + wgt[3][0];
        sm1 += wgt[0][1] + wgt[1][1] + wgt[2][1] + wgt[3][1];
        sm2 += wgt[0][2] + wgt[1][2] + wgt[2][2] + wgt[3][2];
        sm3 += wgt[0][3] + wgt[1][3] + wgt[2][3] + wgt[3][3];
        #pragma unroll
        for (int j = 0; j < 4; ++j) {
            float x0 = bf2f(X0[j]), x1 = bf2f(X1[j]);
            float x2 = bf2f(X2[j]), x3 = bf2f(X3[j]);
            #pragma unroll
            for (int h = 0; h < 4; ++h) {
                float a = acc[h][j];
                a = fmaf(wgt[0][h], x0, a);
                a = fmaf(wgt[1][h], x1, a);
                a = fmaf(wgt[2][h], x2, a);
                a = fmaf(wgt[3][h], x3, a);
                acc[h][j] = a;
            }
        }
    }
    for (; e < deg; ++e) {
        int s = __shfl(sidx, e);
        float4 as = *(const float4*)(a_src + s * H_HEADS);
        bf16x4 x = *(const bf16x4*)(x_ln + (size_t)s * D_MODEL + lane * 4);
        float l0 = as.x + ad.x, l1 = as.y + ad.y,
              l2 = as.z + ad.z, l3 = as.w + ad.w;
        l0 = (l0 > 0.f) ? l0 : 0.2f * l0;
        l1 = (l1 > 0.f) ? l1 : 0.2f * l1;
        l2 = (l2 > 0.f) ? l2 : 0.2f * l2;
        l3 = (l3 > 0.f) ? l3 : 0.2f * l3;
        float w0 = __expf(l0), w1 = __expf(l1);
        float w2 = __expf(l2), w3 = __expf(l3);
        sm0 += w0; sm1 += w1; sm2 += w2; sm3 += w3;
        #pragma unroll
        for (int j = 0; j < 4; ++j) {
            float xv = bf2f(x[j]);
            acc[0][j] = fmaf(w0, xv, acc[0][j]);
            acc[1][j] = fmaf(w1, xv, acc[1][j]);
            acc[2][j] = fmaf(w2, xv, acc[2][j]);
            acc[3][j] = fmaf(w3, xv, acc[3][j]);
        }
    }
    float sc[4] = {0.25f / sm0, 0.25f / sm1, 0.25f / sm2, 0.25f / sm3};
    #pragma unroll
    for (int h = 0; h < 4; ++h) {
        bf16x4 o;
        #pragma unroll
        for (int j = 0; j < 4; ++j) o[j] = f2bf(acc[h][j] * sc[h]);
        *(bf16x4*)(agg + (size_t)i * HC + h * 256 + lane * 4) = o;
    }
}

// -------- K4: skinny bf16 GEMM (one block per 64-row A-panel, full N) --------
#define APAD 72

__global__ __launch_bounds__(256) void gemm_skinny(
    const __bf16* __restrict__ A, const __bf16* __restrict__ B,
    const float* __restrict__ bias, const float* __restrict__ resid,
    float* __restrict__ outf, int K)
{
    __shared__ __align__(16) __bf16 As[64 * APAD];
    __shared__ __align__(16) __bf16 Bs[256 * APAD];
    int tid  = threadIdx.x;
    int lane = tid & 63;
    int w    = tid >> 6;
    int quad = lane >> 4;
    int l16  = lane & 15;
    int m0 = blockIdx.x * 64;
    int n0 = w * 64;

    int srow = tid >> 3, sp = tid & 7;
    const __bf16* Ab = A + (size_t)(m0 + srow) * K + sp * 8;
    const __bf16* Bb = B + (size_t)srow * K + sp * 8;
    size_t rstride = (size_t)32 * K;

    f32x4 acc[4][4] = {};

    bf16x8 a0_0, a0_1, b0_[8];
    bf16x8 a1_0, a1_1, b1_[8];

    auto compute = [&]() {
        #pragma unroll
        for (int ks = 0; ks < 2; ++ks) {
            bf16x8 af[4], bfr[4];
            #pragma unroll
            for (int mt = 0; mt < 4; ++mt)
                af[mt] = *(const bf16x8*)(As + (mt * 16 + l16) * APAD
                                          + ks * 32 + quad * 8);
            #pragma unroll
            for (int nt = 0; nt < 4; ++nt)
                bfr[nt] = *(const bf16x8*)(Bs + (n0 + nt * 16 + l16) * APAD
                                           + ks * 32 + quad * 8);
            #pragma unroll
            for (int mt = 0; mt < 4; ++mt)
                #pragma unroll
                for (int nt = 0; nt < 4; ++nt)
                    acc[mt][nt] = __builtin_amdgcn_mfma_f32_16x16x32_bf16(
                        af[mt], bfr[nt], acc[mt][nt], 0, 0, 0);
        }
    };

    a0_0 = *(const bf16x8*)(Ab);
    a0_1 = *(const bf16x8*)(Ab + rstride);
    #pragma unroll
    for (int t = 0; t < 8; ++t)
        b0_[t] = *(const bf16x8*)(Bb + t * rstride);

    for (int kb = 0; kb < K; kb += 128) {
        {
            const __bf16* Ap = Ab + kb + 64;
            const __bf16* Bp = Bb + kb + 64;
            a1_0 = *(const bf16x8*)(Ap);
            a1_1 = *(const bf16x8*)(Ap + rstride);
            #pragma unroll
            for (int t = 0; t < 8; ++t)
                b1_[t] = *(const bf16x8*)(Bp + t * rstride);
        }
        __syncthreads();
        *(bf16x8*)(As + srow * APAD + sp * 8)        = a0_0;
        *(bf16x8*)(As + (srow + 32) * APAD + sp * 8) = a0_1;
        #pragma unroll
        for (int t = 0; t < 8; ++t)
            *(bf16x8*)(Bs + (srow + t * 32) * APAD + sp * 8) = b0_[t];
        __syncthreads();
        compute();

        if (kb + 128 < K) {
            const __bf16* Ap = Ab + kb + 128;
            const __bf16* Bp = Bb + kb + 128;
            a0_0 = *(const bf16x8*)(Ap);
            a0_1 = *(const bf16x8*)(Ap + rstride);
            #pragma unroll
            for (int t = 0; t < 8; ++t)
                b0_[t] = *(const bf16x8*)(Bp + t * rstride);
        }
        __syncthreads();
        *(bf16x8*)(As + srow * APAD + sp * 8)        = a1_0;
        *(bf16x8*)(As + (srow + 32) * APAD + sp * 8) = a1_1;
        #pragma unroll
        for (int t = 0; t < 8; ++t)
            *(bf16x8*)(Bs + (srow + t * 32) * APAD + sp * 8) = b1_[t];
        __syncthreads();
        compute();
    }

    #pragma unroll
    for (int nt = 0; nt < 4; ++nt) {
        int col = n0 + nt * 16 + l16;
        float bv = bias[col];
        #pragma unroll
        for (int mt = 0; mt < 4; ++mt) {
            int row = m0 + mt * 16 + quad * 4;
            #pragma unroll
            for (int r = 0; r < 4; ++r) {
                size_t off = (size_t)(row + r) * C_CH + col;
                outf[off] = acc[mt][nt][r] + bv + resid[off];
            }
        }
    }
}

extern "C" void kernel_launch(void* const* d_in, const int* in_sizes, int n_in,
                              void* d_out, int out_size, void* d_ws, size_t ws_size,
                              hipStream_t stream)
{
    const float* inp      = (const float*)d_in[0];
    const int*   ei       = (const int*)  d_in[1];
    const float* ln_gamma = (const float*)d_in[2];
    const float* ln_beta  = (const float*)d_in[3];
    const float* W1       = (const float*)d_in[4];
    const float* b1       = (const float*)d_in[5];
    const float* W_gat    = (const float*)d_in[6];
    const float* att_src  = (const float*)d_in[7];
    const float* att_dst  = (const float*)d_in[8];
    const float* bias_gat = (const float*)d_in[9];
    const float* W2       = (const float*)d_in[10];
    const float* b2       = (const float*)d_in[11];

    char* ws = (char*)d_ws;
    __bf16* x_ln_bf = (__bf16*)(ws);                         //  8 MB
    __bf16* agg_bf  = (__bf16*)(ws + (8ull  << 20));         // 32 MB
    __bf16* Wz_b    = (__bf16*)(ws + (40ull << 20));         // 512 KB
    float*  a_src_b = (float*)(ws + (41ull << 20));          // 256 KB
    float*  a_dst_b = a_src_b + (size_t)N_NODES * H_HEADS;   // 256 KB
    float*  u2      = (float*)(ws + (42ull << 20));          //  8 KB
    float*  c0      = u2 + 8 * 256;                          //  32 B
    // ---- zero region start ----
    float*  bias_z  = c0 + 8;                                //  1 KB
    int*    cnt     = (int*)(bias_z + 256);                  // 64 KB
    // ---- zero region end ----
    int*    csr     = (int*)(ws + (43ull << 20));            //  4 MB

    size_t zbytes = 256 * sizeof(float) + N_NODES * sizeof(int);
    hipMemsetAsync(bias_z, 0, zbytes, stream);

    fused_prep_ln<<<577 + 4096, 256, 0, stream>>>(
        W_gat, att_src, att_dst, W1, b1, W2, bias_gat, b2, ei,
        inp, ln_gamma, ln_beta, x_ln_bf, Wz_b, bias_z, u2, c0, cnt, csr);
    logits_k<<<N_NODES / 4, 256, 0, stream>>>(x_ln_bf, u2, c0,
                                              a_src_b, a_dst_b);
    gat_fused<<<N_NODES / 4, 256, 0, stream>>>(x_ln_bf, a_src_b, a_dst_b,
                                               cnt, csr, agg_bf);
    gemm_skinny<<<N_NODES / 64, 256, 0, stream>>>(agg_bf, Wz_b, bias_z, inp,
                                                  (float*)d_out, HC);
}

// Round 6
// 165.167 us; speedup vs baseline: 1.2379x; 1.2379x over previous
//
#include <hip/hip_runtime.h>
#include <math.h>

#define N_NODES 16384
#define D_MODEL 256
#define H_HEADS 4
#define C_CH 256
#define E_EDGES 65536
#define ETOT (E_EDGES + N_NODES)
#define HC 1024

typedef __bf16 bf16x8 __attribute__((ext_vector_type(8)));
typedef __bf16 bf16x4 __attribute__((ext_vector_type(4)));
typedef float f32x4 __attribute__((ext_vector_type(4)));

__device__ __forceinline__ __bf16 f2bf(float f) { return (__bf16)f; }
__device__ __forceinline__ float bf2f(__bf16 b) { return (float)b; }

// ==== K1: 0..63 t-partials | 64..1087 V-compose split-c (64-iter chains) |
//          1088..1407 deg-hist | 1408..5503 LayerNorm ====
// Weight-prep chains capped at 64 iterations; V accumulated via f32 atomics
// (distinct addresses, 4 contributors each) so the compose grid is 1024 blocks
// (>=4/CU) instead of a 256-block 1-block/CU latency tail (r5: 73-96us).
__global__ __launch_bounds__(256) void prep1_ln(
    const float* __restrict__ Wg, const float* __restrict__ att_src,
    const float* __restrict__ att_dst, const float* __restrict__ W2,
    const int* __restrict__ ei, const float* __restrict__ in,
    const float* __restrict__ gamma, const float* __restrict__ beta,
    float* __restrict__ t, float* __restrict__ V, int* __restrict__ deg,
    __bf16* __restrict__ x_ln)
{
    int b = blockIdx.x;
    int tid = threadIdx.x;
    if (b >= 1408) {
        int wave = tid >> 6, lane = tid & 63;
        int row = (b - 1408) * 4 + wave;
        float4 v = ((const float4*)(in + (size_t)row * D_MODEL))[lane];
        float s  = v.x + v.y + v.z + v.w;
        float sq = v.x*v.x + v.y*v.y + v.z*v.z + v.w*v.w;
        for (int off = 32; off; off >>= 1) {
            s  += __shfl_xor(s,  off);
            sq += __shfl_xor(sq, off);
        }
        float mean = s * (1.0f / D_MODEL);
        float var  = sq * (1.0f / D_MODEL) - mean * mean;
        float inv  = rsqrtf(var + 1e-6f);
        float4 g = ((const float4*)gamma)[lane];
        float4 bb = ((const float4*)beta)[lane];
        bf16x4 o;
        o[0] = f2bf((v.x - mean) * inv * g.x + bb.x);
        o[1] = f2bf((v.y - mean) * inv * g.y + bb.y);
        o[2] = f2bf((v.z - mean) * inv * g.z + bb.z);
        o[3] = f2bf((v.w - mean) * inv * g.w + bb.w);
        *(bf16x4*)(x_ln + (size_t)row * D_MODEL + lane * 4) = o;
        return;
    }
    if (b < 64) {
        int v = b >> 3, sl = b & 7, h = v & 3;
        const float* att = ((v < 4) ? att_src : att_dst) + h * C_CH;
        float acc = 0.f;
        #pragma unroll
        for (int j = 0; j < 32; ++j) {
            int c = sl * 32 + j;
            acc = fmaf(Wg[(size_t)(h * 256 + c) * 256 + tid], att[c], acc);
        }
        atomicAdd(&t[v * 256 + tid], acc);
        return;
    }
    if (b < 1088) {
        // V[og+j, h, :] partial over one 64-wide c-slice
        int bb2 = b - 64;
        int orig = bb2 >> 2, cs = bb2 & 3;
        int og = (orig & 63) * 4, h = orig >> 6;
        const float* w2r = W2 + (size_t)og * 256;
        const float* wgp = Wg + ((size_t)h * 256) * 256 + tid;
        float a0 = 0.f, a1 = 0.f, a2 = 0.f, a3 = 0.f;
        int cb = cs * 64;
        #pragma unroll 4
        for (int c = cb; c < cb + 64; ++c) {
            float wv = wgp[(size_t)c * 256];
            a0 = fmaf(w2r[c],       wv, a0);
            a1 = fmaf(w2r[256 + c], wv, a1);
            a2 = fmaf(w2r[512 + c], wv, a2);
            a3 = fmaf(w2r[768 + c], wv, a3);
        }
        size_t base = (size_t)og * 1024 + h * 256 + tid;
        atomicAdd(&V[base],        a0);
        atomicAdd(&V[base + 1024], a1);
        atomicAdd(&V[base + 2048], a2);
        atomicAdd(&V[base + 3072], a3);
        return;
    }
    {
        int e = (b - 1088) * 256 + tid;
        int dst = (e < E_EDGES) ? ei[E_EDGES + e] : (e - E_EDGES);
        atomicAdd(deg + dst, 1);
    }
}

// ==== K2: 0..1023 Wz split-k (f32 partials) + bias_z | 1024..1087 u2/c0 |
//          1088 scan (int4-vectorized) ====
__global__ __launch_bounds__(256) void prep2(
    const float* __restrict__ t, const float* __restrict__ W1,
    const float* __restrict__ b1, const float* __restrict__ V,
    const float* __restrict__ W2, const float* __restrict__ bg,
    const float* __restrict__ b2, float* __restrict__ u2,
    float* __restrict__ c0, float* __restrict__ Wzf,
    float* __restrict__ bias_z, const int* __restrict__ deg,
    int* __restrict__ row_st)
{
    __shared__ float red[4][4];
    __shared__ int wsum[4];
    int b = blockIdx.x;
    int d = threadIdx.x;

    if (b < 1024) {
        int orig = b >> 2, ks = b & 3;
        int og = (orig & 63) * 4, h = orig >> 6;
        int lane = d & 63, wid = d >> 6;
        const float* vr = V + (size_t)og * 1024 + h * 256;
        float a0 = 0.f, a1 = 0.f, a2 = 0.f, a3 = 0.f;
        int kb = ks * 64;
        #pragma unroll 4
        for (int k = kb; k < kb + 64; ++k) {
            float w1v = W1[(size_t)k * 256 + d];
            a0 = fmaf(vr[k],        w1v, a0);
            a1 = fmaf(vr[1024 + k], w1v, a1);
            a2 = fmaf(vr[2048 + k], w1v, a2);
            a3 = fmaf(vr[3072 + k], w1v, a3);
        }
        size_t base = (size_t)og * 1024 + h * 256 + d;
        atomicAdd(&Wzf[base],        a0);
        atomicAdd(&Wzf[base + 1024], a1);
        atomicAdd(&Wzf[base + 2048], a2);
        atomicAdd(&Wzf[base + 3072], a3);

        if (ks == 0) {
            float b1v = b1[d];
            #pragma unroll
            for (int j = 0; j < 4; ++j) {
                float p = vr[(size_t)j * 1024 + d] * b1v;
                for (int s = 32; s; s >>= 1) p += __shfl_xor(p, s);
                if (lane == 0) red[j][wid] = p;
            }
            __syncthreads();
            if (d < 4) {
                float s = red[d][0] + red[d][1] + red[d][2] + red[d][3];
                atomicAdd(&bias_z[og + d], 0.25f * s);
            }
            if (h == 0) {
                __syncthreads();
                float bgv = bg[d];
                #pragma unroll
                for (int j = 0; j < 4; ++j) {
                    float q = W2[(size_t)(og + j) * 256 + d] * bgv;
                    for (int s = 32; s; s >>= 1) q += __shfl_xor(q, s);
                    if (lane == 0) red[j][wid] = q;
                }
                __syncthreads();
                if (d < 4) {
                    float s = red[d][0] + red[d][1] + red[d][2] + red[d][3];
                    atomicAdd(&bias_z[og + d], s + b2[og + d]);
                }
            }
        }
        return;
    }
    if (b < 1088) {
        int bb = b - 1024;
        int v = bb >> 3, sl = bb & 7;
        const float* tv = t + v * 256;
        float acc = 0.f;
        #pragma unroll
        for (int j = 0; j < 32; ++j) {
            int k = sl * 32 + j;
            acc = fmaf(tv[k], W1[(size_t)k * 256 + d], acc);
        }
        atomicAdd(&u2[v * 256 + d], acc);
        if (d < 32) {
            float p = tv[sl * 32 + d] * b1[sl * 32 + d];
            for (int s = 16; s; s >>= 1) p += __shfl_xor(p, s);
            if (d == 0) atomicAdd(&c0[v], p);
        }
        return;
    }
    {
        // scan: int4 loads give 16-deep ILP instead of a 64-deep serial chain
        int lane = d & 63, wid = d >> 6;
        int base = d * 64;
        int4 dv[16];
        #pragma unroll
        for (int j = 0; j < 16; ++j) dv[j] = ((const int4*)(deg + base))[j];
        int run = 0;
        #pragma unroll
        for (int j = 0; j < 16; ++j)
            run += dv[j].x + dv[j].y + dv[j].z + dv[j].w;
        int x = run;
        #pragma unroll
        for (int off = 1; off < 64; off <<= 1) {
            int y = __shfl_up(x, off);
            if (lane >= off) x += y;
        }
        if (lane == 63) wsum[wid] = x;
        __syncthreads();
        int woff = 0;
        #pragma unroll
        for (int wdx = 0; wdx < 4; ++wdx)
            if (wdx < wid) woff += wsum[wdx];
        int excl = woff + x - run;
        int r2v = 0;
        #pragma unroll
        for (int j = 0; j < 16; ++j) {
            int4 w;
            w.x = excl + r2v; r2v += dv[j].x;
            w.y = excl + r2v; r2v += dv[j].y;
            w.z = excl + r2v; r2v += dv[j].z;
            w.w = excl + r2v; r2v += dv[j].w;
            ((int4*)(row_st + base))[j] = w;
        }
        if (d == 255) row_st[N_NODES] = excl + r2v;
    }
}

// ==== K3: 0..4095 logits | 4096..4415 scatter | 4416..4671 Wz f32->bf16 ====
__global__ __launch_bounds__(256) void logits_scatter_cvt(
    const __bf16* __restrict__ x_ln, const float* __restrict__ u2,
    const float* __restrict__ c0, float* __restrict__ a_src,
    float* __restrict__ a_dst, const int* __restrict__ ei,
    const int* __restrict__ row_st, int* __restrict__ cnt,
    int* __restrict__ csr_src, const float* __restrict__ Wzf,
    __bf16* __restrict__ Wz)
{
    int b = blockIdx.x;
    int tid = threadIdx.x;
    if (b >= 4416) {
        int idx = (b - 4416) * 256 + tid;    // 65536 float4 groups = 262144 elems
        float4 v = ((const float4*)Wzf)[idx];
        bf16x4 o;
        o[0] = f2bf(v.x); o[1] = f2bf(v.y); o[2] = f2bf(v.z); o[3] = f2bf(v.w);
        *(bf16x4*)(Wz + (size_t)idx * 4) = o;
        return;
    }
    if (b >= 4096) {
        int e = (b - 4096) * 256 + tid;
        int src, dst;
        if (e < E_EDGES) { src = ei[e]; dst = ei[E_EDGES + e]; }
        else             { src = dst = e - E_EDGES; }
        int pos = atomicAdd(cnt + dst, 1);
        csr_src[row_st[dst] + pos] = src;
        return;
    }
    __shared__ float u2s[8][256];
    __shared__ float c0s[8];
    #pragma unroll
    for (int k = 0; k < 8; ++k) u2s[k][tid] = u2[k * 256 + tid];
    if (tid < 8) c0s[tid] = c0[tid];
    __syncthreads();

    int wave = tid >> 6, lane = tid & 63;
    int n = b * 4 + wave;
    int v = lane >> 3, p = lane & 7;
    const __bf16* xp = x_ln + (size_t)n * D_MODEL + p * 32;
    const float*  up = &u2s[v][p * 32];
    float acc = 0.f;
    #pragma unroll
    for (int ti = 0; ti < 4; ++ti) {
        bf16x8 x = *(const bf16x8*)(xp + ti * 8);
        #pragma unroll
        for (int j = 0; j < 8; ++j)
            acc = fmaf(bf2f(x[j]), up[ti * 8 + j], acc);
    }
    acc += __shfl_xor(acc, 1);
    acc += __shfl_xor(acc, 2);
    acc += __shfl_xor(acc, 4);
    if (p == 0) {
        float o = acc + c0s[v];
        if (v < 4) a_src[n * H_HEADS + v] = o;
        else       a_dst[n * H_HEADS + (v - 4)] = o;
    }
}

// ---- K4: fused softmax + aggregation (unroll-2 gather chains) ----
__global__ __launch_bounds__(256) void gat_fused(
    const __bf16* __restrict__ x_ln, const float* __restrict__ a_src,
    const float* __restrict__ a_dst, const int* __restrict__ row_start,
    const int* __restrict__ csr_src, __bf16* __restrict__ agg)
{
    int wave = threadIdx.x >> 6, lane = threadIdx.x & 63;
    int i = blockIdx.x * 4 + wave;
    int rs = row_start[i], deg = row_start[i + 1] - rs;
    float4 ad = *(const float4*)(a_dst + i * H_HEADS);

    float acc[4][4] = {};
    float sm0 = 0.f, sm1 = 0.f, sm2 = 0.f, sm3 = 0.f;
    int e = 0;
    for (; e + 2 <= deg; e += 2) {
        int s0 = csr_src[rs + e];
        int s1 = csr_src[rs + e + 1];
        float4 as0 = *(const float4*)(a_src + s0 * H_HEADS);
        float4 as1 = *(const float4*)(a_src + s1 * H_HEADS);
        bf16x4 x0 = *(const bf16x4*)(x_ln + (size_t)s0 * D_MODEL + lane * 4);
        bf16x4 x1 = *(const bf16x4*)(x_ln + (size_t)s1 * D_MODEL + lane * 4);
        float l00 = as0.x + ad.x, l01 = as0.y + ad.y,
              l02 = as0.z + ad.z, l03 = as0.w + ad.w;
        float l10 = as1.x + ad.x, l11 = as1.y + ad.y,
              l12 = as1.z + ad.z, l13 = as1.w + ad.w;
        l00 = (l00 > 0.f) ? l00 : 0.2f * l00;
        l01 = (l01 > 0.f) ? l01 : 0.2f * l01;
        l02 = (l02 > 0.f) ? l02 : 0.2f * l02;
        l03 = (l03 > 0.f) ? l03 : 0.2f * l03;
        l10 = (l10 > 0.f) ? l10 : 0.2f * l10;
        l11 = (l11 > 0.f) ? l11 : 0.2f * l11;
        l12 = (l12 > 0.f) ? l12 : 0.2f * l12;
        l13 = (l13 > 0.f) ? l13 : 0.2f * l13;
        float w00 = __expf(l00), w01 = __expf(l01),
              w02 = __expf(l02), w03 = __expf(l03);
        float w10 = __expf(l10), w11 = __expf(l11),
              w12 = __expf(l12), w13 = __expf(l13);
        sm0 += w00 + w10; sm1 += w01 + w11;
        sm2 += w02 + w12; sm3 += w03 + w13;
        #pragma unroll
        for (int j = 0; j < 4; ++j) {
            float xv0 = bf2f(x0[j]);
            float xv1 = bf2f(x1[j]);
            acc[0][j] = fmaf(w00, xv0, acc[0][j]);
            acc[1][j] = fmaf(w01, xv0, acc[1][j]);
            acc[2][j] = fmaf(w02, xv0, acc[2][j]);
            acc[3][j] = fmaf(w03, xv0, acc[3][j]);
            acc[0][j] = fmaf(w10, xv1, acc[0][j]);
            acc[1][j] = fmaf(w11, xv1, acc[1][j]);
            acc[2][j] = fmaf(w12, xv1, acc[2][j]);
            acc[3][j] = fmaf(w13, xv1, acc[3][j]);
        }
    }
    if (e < deg) {
        int s = csr_src[rs + e];
        float4 as = *(const float4*)(a_src + s * H_HEADS);
        bf16x4 x = *(const bf16x4*)(x_ln + (size_t)s * D_MODEL + lane * 4);
        float l0 = as.x + ad.x, l1 = as.y + ad.y,
              l2 = as.z + ad.z, l3 = as.w + ad.w;
        l0 = (l0 > 0.f) ? l0 : 0.2f * l0;
        l1 = (l1 > 0.f) ? l1 : 0.2f * l1;
        l2 = (l2 > 0.f) ? l2 : 0.2f * l2;
        l3 = (l3 > 0.f) ? l3 : 0.2f * l3;
        float w0 = __expf(l0), w1 = __expf(l1);
        float w2 = __expf(l2), w3 = __expf(l3);
        sm0 += w0; sm1 += w1; sm2 += w2; sm3 += w3;
        #pragma unroll
        for (int j = 0; j < 4; ++j) {
            float xv = bf2f(x[j]);
            acc[0][j] = fmaf(w0, xv, acc[0][j]);
            acc[1][j] = fmaf(w1, xv, acc[1][j]);
            acc[2][j] = fmaf(w2, xv, acc[2][j]);
            acc[3][j] = fmaf(w3, xv, acc[3][j]);
        }
    }
    float sc[4] = {0.25f / sm0, 0.25f / sm1, 0.25f / sm2, 0.25f / sm3};
    #pragma unroll
    for (int h = 0; h < 4; ++h) {
        bf16x4 o;
        #pragma unroll
        for (int j = 0; j < 4; ++j) o[j] = f2bf(acc[h][j] * sc[h]);
        *(bf16x4*)(agg + (size_t)i * HC + h * 256 + lane * 4) = o;
    }
}

// -------- K5: skinny bf16 GEMM (one block per 64-row A-panel, full N) --------
#define APAD 72

__global__ __launch_bounds__(256) void gemm_skinny(
    const __bf16* __restrict__ A, const __bf16* __restrict__ B,
    const float* __restrict__ bias, const float* __restrict__ resid,
    float* __restrict__ outf, int K)
{
    __shared__ __align__(16) __bf16 As[64 * APAD];
    __shared__ __align__(16) __bf16 Bs[256 * APAD];
    int tid  = threadIdx.x;
    int lane = tid & 63;
    int w    = tid >> 6;
    int quad = lane >> 4;
    int l16  = lane & 15;
    int m0 = blockIdx.x * 64;
    int n0 = w * 64;

    int srow = tid >> 3, sp = tid & 7;
    const __bf16* Ab = A + (size_t)(m0 + srow) * K + sp * 8;
    const __bf16* Bb = B + (size_t)srow * K + sp * 8;
    size_t rstride = (size_t)32 * K;

    f32x4 acc[4][4] = {};

    bf16x8 a0_0, a0_1, b0_[8];
    bf16x8 a1_0, a1_1, b1_[8];

    auto compute = [&]() {
        #pragma unroll
        for (int ks = 0; ks < 2; ++ks) {
            bf16x8 af[4], bfr[4];
            #pragma unroll
            for (int mt = 0; mt < 4; ++mt)
                af[mt] = *(const bf16x8*)(As + (mt * 16 + l16) * APAD
                                          + ks * 32 + quad * 8);
            #pragma unroll
            for (int nt = 0; nt < 4; ++nt)
                bfr[nt] = *(const bf16x8*)(Bs + (n0 + nt * 16 + l16) * APAD
                                           + ks * 32 + quad * 8);
            #pragma unroll
            for (int mt = 0; mt < 4; ++mt)
                #pragma unroll
                for (int nt = 0; nt < 4; ++nt)
                    acc[mt][nt] = __builtin_amdgcn_mfma_f32_16x16x32_bf16(
                        af[mt], bfr[nt], acc[mt][nt], 0, 0, 0);
        }
    };

    a0_0 = *(const bf16x8*)(Ab);
    a0_1 = *(const bf16x8*)(Ab + rstride);
    #pragma unroll
    for (int t = 0; t < 8; ++t)
        b0_[t] = *(const bf16x8*)(Bb + t * rstride);

    for (int kb = 0; kb < K; kb += 128) {
        {
            const __bf16* Ap = Ab + kb + 64;
            const __bf16* Bp = Bb + kb + 64;
            a1_0 = *(const bf16x8*)(Ap);
            a1_1 = *(const bf16x8*)(Ap + rstride);
            #pragma unroll
            for (int t = 0; t < 8; ++t)
                b1_[t] = *(const bf16x8*)(Bp + t * rstride);
        }
        __syncthreads();
        *(bf16x8*)(As + srow * APAD + sp * 8)        = a0_0;
        *(bf16x8*)(As + (srow + 32) * APAD + sp * 8) = a0_1;
        #pragma unroll
        for (int t = 0; t < 8; ++t)
            *(bf16x8*)(Bs + (srow + t * 32) * APAD + sp * 8) = b0_[t];
        __syncthreads();
        compute();

        if (kb + 128 < K) {
            const __bf16* Ap = Ab + kb + 128;
            const __bf16* Bp = Bb + kb + 128;
            a0_0 = *(const bf16x8*)(Ap);
            a0_1 = *(const bf16x8*)(Ap + rstride);
            #pragma unroll
            for (int t = 0; t < 8; ++t)
                b0_[t] = *(const bf16x8*)(Bp + t * rstride);
        }
        __syncthreads();
        *(bf16x8*)(As + srow * APAD + sp * 8)        = a1_0;
        *(bf16x8*)(As + (srow + 32) * APAD + sp * 8) = a1_1;
        #pragma unroll
        for (int t = 0; t < 8; ++t)
            *(bf16x8*)(Bs + (srow + t * 32) * APAD + sp * 8) = b1_[t];
        __syncthreads();
        compute();
    }

    #pragma unroll
    for (int nt = 0; nt < 4; ++nt) {
        int col = n0 + nt * 16 + l16;
        float bv = bias[col];
        #pragma unroll
        for (int mt = 0; mt < 4; ++mt) {
            int row = m0 + mt * 16 + quad * 4;
            #pragma unroll
            for (int r = 0; r < 4; ++r) {
                size_t off = (size_t)(row + r) * C_CH + col;
                outf[off] = acc[mt][nt][r] + bv + resid[off];
            }
        }
    }
}

extern "C" void kernel_launch(void* const* d_in, const int* in_sizes, int n_in,
                              void* d_out, int out_size, void* d_ws, size_t ws_size,
                              hipStream_t stream)
{
    const float* inp      = (const float*)d_in[0];
    const int*   ei       = (const int*)  d_in[1];
    const float* ln_gamma = (const float*)d_in[2];
    const float* ln_beta  = (const float*)d_in[3];
    const float* W1       = (const float*)d_in[4];
    const float* b1       = (const float*)d_in[5];
    const float* W_gat    = (const float*)d_in[6];
    const float* att_src  = (const float*)d_in[7];
    const float* att_dst  = (const float*)d_in[8];
    const float* bias_gat = (const float*)d_in[9];
    const float* W2       = (const float*)d_in[10];
    const float* b2       = (const float*)d_in[11];

    char* ws = (char*)d_ws;
    __bf16* x_ln_bf = (__bf16*)(ws);                         //  8 MB
    __bf16* agg_bf  = (__bf16*)(ws + (8ull  << 20));         // 32 MB
    __bf16* Wz_b    = (__bf16*)(ws + (40ull << 20));         // 512 KB
    float*  a_src_b = (float*)(ws + (41ull << 20));          // 256 KB
    float*  a_dst_b = a_src_b + (size_t)N_NODES * H_HEADS;   // 256 KB
    // ---- zero region start (42 MB, 16B aligned throughout) ----
    float*  t_vec   = (float*)(ws + (42ull << 20));          //  8 KB
    float*  u2      = t_vec + 2048;                          //  8 KB
    float*  c0      = u2 + 2048;                             //  32 B
    float*  bias_z  = c0 + 8;                                //  1 KB
    int*    deg     = (int*)(bias_z + 256);                  // 64 KB
    int*    cnt     = deg + N_NODES;                         // 64 KB
    float*  V_f     = (float*)(cnt + N_NODES);               //  1 MB
    float*  Wzf     = V_f + 256 * 1024;                      //  1 MB
    // ---- zero region end ----
    int*    row_st  = (int*)(Wzf + 256 * 1024);
    int*    csr_src = row_st + N_NODES + 4;

    size_t zbytes = (2048 + 2048 + 8 + 256) * sizeof(float)
                  + 2 * N_NODES * sizeof(int)
                  + 2 * 256 * 1024 * sizeof(float);
    hipMemsetAsync(t_vec, 0, zbytes, stream);

    prep1_ln<<<1408 + 4096, 256, 0, stream>>>(W_gat, att_src, att_dst, W2, ei,
                                              inp, ln_gamma, ln_beta,
                                              t_vec, V_f, deg, x_ln_bf);
    prep2<<<1089, 256, 0, stream>>>(t_vec, W1, b1, V_f, W2, bias_gat, b2,
                                    u2, c0, Wzf, bias_z, deg, row_st);
    logits_scatter_cvt<<<4096 + 320 + 256, 256, 0, stream>>>(
        x_ln_bf, u2, c0, a_src_b, a_dst_b, ei, row_st, cnt, csr_src,
        Wzf, Wz_b);
    gat_fused<<<N_NODES / 4, 256, 0, stream>>>(x_ln_bf, a_src_b, a_dst_b,
                                               row_st, csr_src, agg_bf);
    gemm_skinny<<<N_NODES / 64, 256, 0, stream>>>(agg_bf, Wz_b, bias_z, inp,
                                                  (float*)d_out, HC);
}

// Round 7
// 163.604 us; speedup vs baseline: 1.2497x; 1.0095x over previous
//
#include <hip/hip_runtime.h>
#include <math.h>

#define N_NODES 16384
#define D_MODEL 256
#define H_HEADS 4
#define C_CH 256
#define E_EDGES 65536
#define ETOT (E_EDGES + N_NODES)
#define HC 1024
#define MAXDEG 64

typedef __bf16 bf16x8 __attribute__((ext_vector_type(8)));
typedef __bf16 bf16x4 __attribute__((ext_vector_type(4)));
typedef float f32x4 __attribute__((ext_vector_type(4)));

__device__ __forceinline__ __bf16 f2bf(float f) { return (__bf16)f; }
__device__ __forceinline__ float bf2f(__bf16 b) { return (float)b; }

// ==== K1: 0..63 t-partials | 64..2111 V-compose split-8 (32-iter chains) |
//          2112..2431 padded-CSR scatter | 2432..6527 LayerNorm ====
// Padded CSR (stride MAXDEG, cnt-atomics) removes the deg-hist pass and the
// serial scan entirely; scatter no longer depends on anything cross-kernel.
__global__ __launch_bounds__(256) void prep1_ln(
    const float* __restrict__ Wg, const float* __restrict__ att_src,
    const float* __restrict__ att_dst, const float* __restrict__ W2,
    const int* __restrict__ ei, const float* __restrict__ in,
    const float* __restrict__ gamma, const float* __restrict__ beta,
    float* __restrict__ t, float* __restrict__ V, int* __restrict__ cnt,
    int* __restrict__ csr, __bf16* __restrict__ x_ln)
{
    int b = blockIdx.x;
    int tid = threadIdx.x;
    if (b >= 2432) {
        int wave = tid >> 6, lane = tid & 63;
        int row = (b - 2432) * 4 + wave;
        float4 v = ((const float4*)(in + (size_t)row * D_MODEL))[lane];
        float s  = v.x + v.y + v.z + v.w;
        float sq = v.x*v.x + v.y*v.y + v.z*v.z + v.w*v.w;
        for (int off = 32; off; off >>= 1) {
            s  += __shfl_xor(s,  off);
            sq += __shfl_xor(sq, off);
        }
        float mean = s * (1.0f / D_MODEL);
        float var  = sq * (1.0f / D_MODEL) - mean * mean;
        float inv  = rsqrtf(var + 1e-6f);
        float4 g = ((const float4*)gamma)[lane];
        float4 bb = ((const float4*)beta)[lane];
        bf16x4 o;
        o[0] = f2bf((v.x - mean) * inv * g.x + bb.x);
        o[1] = f2bf((v.y - mean) * inv * g.y + bb.y);
        o[2] = f2bf((v.z - mean) * inv * g.z + bb.z);
        o[3] = f2bf((v.w - mean) * inv * g.w + bb.w);
        *(bf16x4*)(x_ln + (size_t)row * D_MODEL + lane * 4) = o;
        return;
    }
    if (b < 64) {
        int v = b >> 3, sl = b & 7, h = v & 3;
        const float* att = ((v < 4) ? att_src : att_dst) + h * C_CH;
        float acc = 0.f;
        #pragma unroll
        for (int j = 0; j < 32; ++j) {
            int c = sl * 32 + j;
            acc = fmaf(Wg[(size_t)(h * 256 + c) * 256 + tid], att[c], acc);
        }
        atomicAdd(&t[v * 256 + tid], acc);
        return;
    }
    if (b < 2112) {
        // V[og+j, h, :] partial over one 32-wide c-slice (8 contributors)
        int bb2 = b - 64;
        int orig = bb2 >> 3, cs = bb2 & 7;
        int og = (orig & 63) * 4, h = orig >> 6;
        const float* w2r = W2 + (size_t)og * 256;
        const float* wgp = Wg + ((size_t)h * 256) * 256 + tid;
        float a0 = 0.f, a1 = 0.f, a2 = 0.f, a3 = 0.f;
        int cb = cs * 32;
        #pragma unroll 4
        for (int c = cb; c < cb + 32; ++c) {
            float wv = wgp[(size_t)c * 256];
            a0 = fmaf(w2r[c],       wv, a0);
            a1 = fmaf(w2r[256 + c], wv, a1);
            a2 = fmaf(w2r[512 + c], wv, a2);
            a3 = fmaf(w2r[768 + c], wv, a3);
        }
        size_t base = (size_t)og * 1024 + h * 256 + tid;
        atomicAdd(&V[base],        a0);
        atomicAdd(&V[base + 1024], a1);
        atomicAdd(&V[base + 2048], a2);
        atomicAdd(&V[base + 3072], a3);
        return;
    }
    {
        // padded-CSR scatter
        int e = (b - 2112) * 256 + tid;
        int src, dst;
        if (e < E_EDGES) { src = ei[e]; dst = ei[E_EDGES + e]; }
        else             { src = dst = e - E_EDGES; }
        int pos = atomicAdd(cnt + dst, 1);
        csr[(size_t)dst * MAXDEG + pos] = src;
    }
}

// ==== K2: 0..2047 Wz split-8 (f32 partials, 32-iter chains) + bias_z |
//          2048..2111 u2/c0 ====
__global__ __launch_bounds__(256) void prep2(
    const float* __restrict__ t, const float* __restrict__ W1,
    const float* __restrict__ b1, const float* __restrict__ V,
    const float* __restrict__ W2, const float* __restrict__ bg,
    const float* __restrict__ b2, float* __restrict__ u2,
    float* __restrict__ c0, float* __restrict__ Wzf,
    float* __restrict__ bias_z)
{
    __shared__ float red[4][4];
    int b = blockIdx.x;
    int d = threadIdx.x;

    if (b < 2048) {
        int orig = b >> 3, ks = b & 7;
        int og = (orig & 63) * 4, h = orig >> 6;
        int lane = d & 63, wid = d >> 6;
        const float* vr = V + (size_t)og * 1024 + h * 256;
        float a0 = 0.f, a1 = 0.f, a2 = 0.f, a3 = 0.f;
        int kb = ks * 32;
        #pragma unroll 4
        for (int k = kb; k < kb + 32; ++k) {
            float w1v = W1[(size_t)k * 256 + d];
            a0 = fmaf(vr[k],        w1v, a0);
            a1 = fmaf(vr[1024 + k], w1v, a1);
            a2 = fmaf(vr[2048 + k], w1v, a2);
            a3 = fmaf(vr[3072 + k], w1v, a3);
        }
        size_t base = (size_t)og * 1024 + h * 256 + d;
        atomicAdd(&Wzf[base],        a0);
        atomicAdd(&Wzf[base + 1024], a1);
        atomicAdd(&Wzf[base + 2048], a2);
        atomicAdd(&Wzf[base + 3072], a3);

        if (ks == 0) {
            float b1v = b1[d];
            #pragma unroll
            for (int j = 0; j < 4; ++j) {
                float p = vr[(size_t)j * 1024 + d] * b1v;
                for (int s = 32; s; s >>= 1) p += __shfl_xor(p, s);
                if (lane == 0) red[j][wid] = p;
            }
            __syncthreads();
            if (d < 4) {
                float s = red[d][0] + red[d][1] + red[d][2] + red[d][3];
                atomicAdd(&bias_z[og + d], 0.25f * s);
            }
            if (h == 0) {
                __syncthreads();
                float bgv = bg[d];
                #pragma unroll
                for (int j = 0; j < 4; ++j) {
                    float q = W2[(size_t)(og + j) * 256 + d] * bgv;
                    for (int s = 32; s; s >>= 1) q += __shfl_xor(q, s);
                    if (lane == 0) red[j][wid] = q;
                }
                __syncthreads();
                if (d < 4) {
                    float s = red[d][0] + red[d][1] + red[d][2] + red[d][3];
                    atomicAdd(&bias_z[og + d], s + b2[og + d]);
                }
            }
        }
        return;
    }
    {
        int bb = b - 2048;
        int v = bb >> 3, sl = bb & 7;
        const float* tv = t + v * 256;
        float acc = 0.f;
        #pragma unroll
        for (int j = 0; j < 32; ++j) {
            int k = sl * 32 + j;
            acc = fmaf(tv[k], W1[(size_t)k * 256 + d], acc);
        }
        atomicAdd(&u2[v * 256 + d], acc);
        if (d < 32) {
            float p = tv[sl * 32 + d] * b1[sl * 32 + d];
            for (int s = 16; s; s >>= 1) p += __shfl_xor(p, s);
            if (d == 0) atomicAdd(&c0[v], p);
        }
    }
}

// ==== K3: 0..4095 logits | 4096..4351 Wz f32->bf16 cvt ====
__global__ __launch_bounds__(256) void logits_cvt(
    const __bf16* __restrict__ x_ln, const float* __restrict__ u2,
    const float* __restrict__ c0, float* __restrict__ a_src,
    float* __restrict__ a_dst, const float* __restrict__ Wzf,
    __bf16* __restrict__ Wz)
{
    int b = blockIdx.x;
    int tid = threadIdx.x;
    if (b >= 4096) {
        int idx = (b - 4096) * 256 + tid;    // 65536 float4 groups
        float4 v = ((const float4*)Wzf)[idx];
        bf16x4 o;
        o[0] = f2bf(v.x); o[1] = f2bf(v.y); o[2] = f2bf(v.z); o[3] = f2bf(v.w);
        *(bf16x4*)(Wz + (size_t)idx * 4) = o;
        return;
    }
    __shared__ float u2s[8][256];
    __shared__ float c0s[8];
    #pragma unroll
    for (int k = 0; k < 8; ++k) u2s[k][tid] = u2[k * 256 + tid];
    if (tid < 8) c0s[tid] = c0[tid];
    __syncthreads();

    int wave = tid >> 6, lane = tid & 63;
    int n = b * 4 + wave;
    int v = lane >> 3, p = lane & 7;
    const __bf16* xp = x_ln + (size_t)n * D_MODEL + p * 32;
    const float*  up = &u2s[v][p * 32];
    float acc = 0.f;
    #pragma unroll
    for (int ti = 0; ti < 4; ++ti) {
        bf16x8 x = *(const bf16x8*)(xp + ti * 8);
        #pragma unroll
        for (int j = 0; j < 8; ++j)
            acc = fmaf(bf2f(x[j]), up[ti * 8 + j], acc);
    }
    acc += __shfl_xor(acc, 1);
    acc += __shfl_xor(acc, 2);
    acc += __shfl_xor(acc, 4);
    if (p == 0) {
        float o = acc + c0s[v];
        if (v < 4) a_src[n * H_HEADS + v] = o;
        else       a_dst[n * H_HEADS + (v - 4)] = o;
    }
}

// ==== K4: fused softmax + aggregation (padded CSR, lane-shfl, unroll-4) ====
// Indices for the whole row loaded by one coalesced lane-load, distributed via
// __shfl — no dependent index load in the gather chain; 4 chains in flight.
__global__ __launch_bounds__(256) void gat_fused(
    const __bf16* __restrict__ x_ln, const float* __restrict__ a_src,
    const float* __restrict__ a_dst, const int* __restrict__ cnt,
    const int* __restrict__ csr, __bf16* __restrict__ agg)
{
    int wave = threadIdx.x >> 6, lane = threadIdx.x & 63;
    int i = blockIdx.x * 4 + wave;
    int deg = cnt[i];
    int sidx = csr[(size_t)i * MAXDEG + lane];   // coalesced; garbage past deg
    float4 ad = *(const float4*)(a_dst + i * H_HEADS);

    float acc[4][4] = {};
    float sm0 = 0.f, sm1 = 0.f, sm2 = 0.f, sm3 = 0.f;

    int e = 0;
    for (; e + 4 <= deg; e += 4) {
        int s0 = __shfl(sidx, e);
        int s1 = __shfl(sidx, e + 1);
        int s2 = __shfl(sidx, e + 2);
        int s3 = __shfl(sidx, e + 3);
        float4 A0 = *(const float4*)(a_src + s0 * H_HEADS);
        float4 A1 = *(const float4*)(a_src + s1 * H_HEADS);
        float4 A2 = *(const float4*)(a_src + s2 * H_HEADS);
        float4 A3 = *(const float4*)(a_src + s3 * H_HEADS);
        bf16x4 X0 = *(const bf16x4*)(x_ln + (size_t)s0 * D_MODEL + lane * 4);
        bf16x4 X1 = *(const bf16x4*)(x_ln + (size_t)s1 * D_MODEL + lane * 4);
        bf16x4 X2 = *(const bf16x4*)(x_ln + (size_t)s2 * D_MODEL + lane * 4);
        bf16x4 X3 = *(const bf16x4*)(x_ln + (size_t)s3 * D_MODEL + lane * 4);

        float l[4][4] = {
            {A0.x + ad.x, A0.y + ad.y, A0.z + ad.z, A0.w + ad.w},
            {A1.x + ad.x, A1.y + ad.y, A1.z + ad.z, A1.w + ad.w},
            {A2.x + ad.x, A2.y + ad.y, A2.z + ad.z, A2.w + ad.w},
            {A3.x + ad.x, A3.y + ad.y, A3.z + ad.z, A3.w + ad.w}};
        float wgt[4][4];
        #pragma unroll
        for (int q = 0; q < 4; ++q)
            #pragma unroll
            for (int h = 0; h < 4; ++h) {
                float lv = l[q][h];
                lv = (lv > 0.f) ? lv : 0.2f * lv;
                wgt[q][h] = __expf(lv);
            }
        sm0 += wgt[0][0] + wgt[1][0] + wgt[2][0] + wgt[3][0];
        sm1 += wgt[0][1] + wgt[1][1] + wgt[2][1] + wgt[3][1];
        sm2 += wgt[0][2] + wgt[1][2] + wgt[2][2] + wgt[3][2];
        sm3 += wgt[0][3] + wgt[1][3] + wgt[2][3] + wgt[3][3];
        #pragma unroll
        for (int j = 0; j < 4; ++j) {
            float x0 = bf2f(X0[j]), x1 = bf2f(X1[j]);
            float x2 = bf2f(X2[j]), x3 = bf2f(X3[j]);
            #pragma unroll
            for (int h = 0; h < 4; ++h) {
                float a = acc[h][j];
                a = fmaf(wgt[0][h], x0, a);
                a = fmaf(wgt[1][h], x1, a);
                a = fmaf(wgt[2][h], x2, a);
                a = fmaf(wgt[3][h], x3, a);
                acc[h][j] = a;
            }
        }
    }
    for (; e < deg; ++e) {
        int s = __shfl(sidx, e);
        float4 as = *(const float4*)(a_src + s * H_HEADS);
        bf16x4 x = *(const bf16x4*)(x_ln + (size_t)s * D_MODEL + lane * 4);
        float l0 = as.x + ad.x, l1 = as.y + ad.y,
              l2 = as.z + ad.z, l3 = as.w + ad.w;
        l0 = (l0 > 0.f) ? l0 : 0.2f * l0;
        l1 = (l1 > 0.f) ? l1 : 0.2f * l1;
        l2 = (l2 > 0.f) ? l2 : 0.2f * l2;
        l3 = (l3 > 0.f) ? l3 : 0.2f * l3;
        float w0 = __expf(l0), w1 = __expf(l1);
        float w2 = __expf(l2), w3 = __expf(l3);
        sm0 += w0; sm1 += w1; sm2 += w2; sm3 += w3;
        #pragma unroll
        for (int j = 0; j < 4; ++j) {
            float xv = bf2f(x[j]);
            acc[0][j] = fmaf(w0, xv, acc[0][j]);
            acc[1][j] = fmaf(w1, xv, acc[1][j]);
            acc[2][j] = fmaf(w2, xv, acc[2][j]);
            acc[3][j] = fmaf(w3, xv, acc[3][j]);
        }
    }
    float sc[4] = {0.25f / sm0, 0.25f / sm1, 0.25f / sm2, 0.25f / sm3};
    #pragma unroll
    for (int h = 0; h < 4; ++h) {
        bf16x4 o;
        #pragma unroll
        for (int j = 0; j < 4; ++j) o[j] = f2bf(acc[h][j] * sc[h]);
        *(bf16x4*)(agg + (size_t)i * HC + h * 256 + lane * 4) = o;
    }
}

// -------- K5: skinny bf16 GEMM (one block per 64-row A-panel, full N) --------
#define APAD 72

__global__ __launch_bounds__(256) void gemm_skinny(
    const __bf16* __restrict__ A, const __bf16* __restrict__ B,
    const float* __restrict__ bias, const float* __restrict__ resid,
    float* __restrict__ outf, int K)
{
    __shared__ __align__(16) __bf16 As[64 * APAD];
    __shared__ __align__(16) __bf16 Bs[256 * APAD];
    int tid  = threadIdx.x;
    int lane = tid & 63;
    int w    = tid >> 6;
    int quad = lane >> 4;
    int l16  = lane & 15;
    int m0 = blockIdx.x * 64;
    int n0 = w * 64;

    int srow = tid >> 3, sp = tid & 7;
    const __bf16* Ab = A + (size_t)(m0 + srow) * K + sp * 8;
    const __bf16* Bb = B + (size_t)srow * K + sp * 8;
    size_t rstride = (size_t)32 * K;

    f32x4 acc[4][4] = {};

    bf16x8 a0_0, a0_1, b0_[8];
    bf16x8 a1_0, a1_1, b1_[8];

    auto compute = [&]() {
        #pragma unroll
        for (int ks = 0; ks < 2; ++ks) {
            bf16x8 af[4], bfr[4];
            #pragma unroll
            for (int mt = 0; mt < 4; ++mt)
                af[mt] = *(const bf16x8*)(As + (mt * 16 + l16) * APAD
                                          + ks * 32 + quad * 8);
            #pragma unroll
            for (int nt = 0; nt < 4; ++nt)
                bfr[nt] = *(const bf16x8*)(Bs + (n0 + nt * 16 + l16) * APAD
                                           + ks * 32 + quad * 8);
            #pragma unroll
            for (int mt = 0; mt < 4; ++mt)
                #pragma unroll
                for (int nt = 0; nt < 4; ++nt)
                    acc[mt][nt] = __builtin_amdgcn_mfma_f32_16x16x32_bf16(
                        af[mt], bfr[nt], acc[mt][nt], 0, 0, 0);
        }
    };

    a0_0 = *(const bf16x8*)(Ab);
    a0_1 = *(const bf16x8*)(Ab + rstride);
    #pragma unroll
    for (int t = 0; t < 8; ++t)
        b0_[t] = *(const bf16x8*)(Bb + t * rstride);

    for (int kb = 0; kb < K; kb += 128) {
        {
            const __bf16* Ap = Ab + kb + 64;
            const __bf16* Bp = Bb + kb + 64;
            a1_0 = *(const bf16x8*)(Ap);
            a1_1 = *(const bf16x8*)(Ap + rstride);
            #pragma unroll
            for (int t = 0; t < 8; ++t)
                b1_[t] = *(const bf16x8*)(Bp + t * rstride);
        }
        __syncthreads();
        *(bf16x8*)(As + srow * APAD + sp * 8)        = a0_0;
        *(bf16x8*)(As + (srow + 32) * APAD + sp * 8) = a0_1;
        #pragma unroll
        for (int t = 0; t < 8; ++t)
            *(bf16x8*)(Bs + (srow + t * 32) * APAD + sp * 8) = b0_[t];
        __syncthreads();
        compute();

        if (kb + 128 < K) {
            const __bf16* Ap = Ab + kb + 128;
            const __bf16* Bp = Bb + kb + 128;
            a0_0 = *(const bf16x8*)(Ap);
            a0_1 = *(const bf16x8*)(Ap + rstride);
            #pragma unroll
            for (int t = 0; t < 8; ++t)
                b0_[t] = *(const bf16x8*)(Bp + t * rstride);
        }
        __syncthreads();
        *(bf16x8*)(As + srow * APAD + sp * 8)        = a1_0;
        *(bf16x8*)(As + (srow + 32) * APAD + sp * 8) = a1_1;
        #pragma unroll
        for (int t = 0; t < 8; ++t)
            *(bf16x8*)(Bs + (srow + t * 32) * APAD + sp * 8) = b1_[t];
        __syncthreads();
        compute();
    }

    #pragma unroll
    for (int nt = 0; nt < 4; ++nt) {
        int col = n0 + nt * 16 + l16;
        float bv = bias[col];
        #pragma unroll
        for (int mt = 0; mt < 4; ++mt) {
            int row = m0 + mt * 16 + quad * 4;
            #pragma unroll
            for (int r = 0; r < 4; ++r) {
                size_t off = (size_t)(row + r) * C_CH + col;
                outf[off] = acc[mt][nt][r] + bv + resid[off];
            }
        }
    }
}

extern "C" void kernel_launch(void* const* d_in, const int* in_sizes, int n_in,
                              void* d_out, int out_size, void* d_ws, size_t ws_size,
                              hipStream_t stream)
{
    const float* inp      = (const float*)d_in[0];
    const int*   ei       = (const int*)  d_in[1];
    const float* ln_gamma = (const float*)d_in[2];
    const float* ln_beta  = (const float*)d_in[3];
    const float* W1       = (const float*)d_in[4];
    const float* b1       = (const float*)d_in[5];
    const float* W_gat    = (const float*)d_in[6];
    const float* att_src  = (const float*)d_in[7];
    const float* att_dst  = (const float*)d_in[8];
    const float* bias_gat = (const float*)d_in[9];
    const float* W2       = (const float*)d_in[10];
    const float* b2       = (const float*)d_in[11];

    char* ws = (char*)d_ws;
    __bf16* x_ln_bf = (__bf16*)(ws);                         //  8 MB
    __bf16* agg_bf  = (__bf16*)(ws + (8ull  << 20));         // 32 MB
    __bf16* Wz_b    = (__bf16*)(ws + (40ull << 20));         // 512 KB
    float*  a_src_b = (float*)(ws + (41ull << 20));          // 256 KB
    float*  a_dst_b = a_src_b + (size_t)N_NODES * H_HEADS;   // 256 KB
    // ---- zero region start (42 MB) ----
    float*  t_vec   = (float*)(ws + (42ull << 20));          //  8 KB
    float*  u2      = t_vec + 2048;                          //  8 KB
    float*  c0      = u2 + 2048;                             //  32 B
    float*  bias_z  = c0 + 8;                                //  1 KB
    int*    cnt     = (int*)(bias_z + 256);                  // 64 KB
    float*  V_f     = (float*)(cnt + N_NODES);               //  1 MB
    float*  Wzf     = V_f + 256 * 1024;                      //  1 MB
    // ---- zero region end ----
    int*    csr     = (int*)(ws + (45ull << 20));            //  4 MB

    size_t zbytes = (2048 + 2048 + 8 + 256) * sizeof(float)
                  + N_NODES * sizeof(int)
                  + 2 * 256 * 1024 * sizeof(float);
    hipMemsetAsync(t_vec, 0, zbytes, stream);

    prep1_ln<<<2432 + 4096, 256, 0, stream>>>(W_gat, att_src, att_dst, W2, ei,
                                              inp, ln_gamma, ln_beta,
                                              t_vec, V_f, cnt, csr, x_ln_bf);
    prep2<<<2112, 256, 0, stream>>>(t_vec, W1, b1, V_f, W2, bias_gat, b2,
                                    u2, c0, Wzf, bias_z);
    logits_cvt<<<4096 + 256, 256, 0, stream>>>(x_ln_bf, u2, c0,
                                               a_src_b, a_dst_b, Wzf, Wz_b);
    gat_fused<<<N_NODES / 4, 256, 0, stream>>>(x_ln_bf, a_src_b, a_dst_b,
                                               cnt, csr, agg_bf);
    gemm_skinny<<<N_NODES / 64, 256, 0, stream>>>(agg_bf, Wz_b, bias_z, inp,
                                                  (float*)d_out, HC);
}

// Round 8
// 155.548 us; speedup vs baseline: 1.3145x; 1.0518x over previous
//
#include <hip/hip_runtime.h>
#include <math.h>

#define N_NODES 16384
#define D_MODEL 256
#define H_HEADS 4
#define C_CH 256
#define E_EDGES 65536
#define ETOT (E_EDGES + N_NODES)
#define HC 1024
#define MAXDEG 64
#define PSZ 262144   // 256*1024 elements per partial buffer

typedef __bf16 bf16x8 __attribute__((ext_vector_type(8)));
typedef __bf16 bf16x4 __attribute__((ext_vector_type(4)));
typedef float f32x4 __attribute__((ext_vector_type(4)));

__device__ __forceinline__ __bf16 f2bf(float f) { return (__bf16)f; }
__device__ __forceinline__ float bf2f(__bf16 b) { return (float)b; }

// ==== K1: 0..63 t-partials | 64..2111 V-compose split-8 -> Vp (plain stores) |
//          2112..2431 padded-CSR scatter | 2432..6527 LayerNorm ====
// Split-8 partials go to 8 disjoint buffers with coalesced stores — the 2M
// f32 atomicAdds this branch used to issue are gone.
__global__ __launch_bounds__(256) void prep1_ln(
    const float* __restrict__ Wg, const float* __restrict__ att_src,
    const float* __restrict__ att_dst, const float* __restrict__ W2,
    const int* __restrict__ ei, const float* __restrict__ in,
    const float* __restrict__ gamma, const float* __restrict__ beta,
    float* __restrict__ t, float* __restrict__ Vp, int* __restrict__ cnt,
    int* __restrict__ csr, __bf16* __restrict__ x_ln)
{
    int b = blockIdx.x;
    int tid = threadIdx.x;
    if (b >= 2432) {
        int wave = tid >> 6, lane = tid & 63;
        int row = (b - 2432) * 4 + wave;
        float4 v = ((const float4*)(in + (size_t)row * D_MODEL))[lane];
        float s  = v.x + v.y + v.z + v.w;
        float sq = v.x*v.x + v.y*v.y + v.z*v.z + v.w*v.w;
        for (int off = 32; off; off >>= 1) {
            s  += __shfl_xor(s,  off);
            sq += __shfl_xor(sq, off);
        }
        float mean = s * (1.0f / D_MODEL);
        float var  = sq * (1.0f / D_MODEL) - mean * mean;
        float inv  = rsqrtf(var + 1e-6f);
        float4 g = ((const float4*)gamma)[lane];
        float4 bb = ((const float4*)beta)[lane];
        bf16x4 o;
        o[0] = f2bf((v.x - mean) * inv * g.x + bb.x);
        o[1] = f2bf((v.y - mean) * inv * g.y + bb.y);
        o[2] = f2bf((v.z - mean) * inv * g.z + bb.z);
        o[3] = f2bf((v.w - mean) * inv * g.w + bb.w);
        *(bf16x4*)(x_ln + (size_t)row * D_MODEL + lane * 4) = o;
        return;
    }
    if (b < 64) {
        int v = b >> 3, sl = b & 7, h = v & 3;
        const float* att = ((v < 4) ? att_src : att_dst) + h * C_CH;
        float acc = 0.f;
        #pragma unroll
        for (int j = 0; j < 32; ++j) {
            int c = sl * 32 + j;
            acc = fmaf(Wg[(size_t)(h * 256 + c) * 256 + tid], att[c], acc);
        }
        atomicAdd(&t[v * 256 + tid], acc);
        return;
    }
    if (b < 2112) {
        // V partial over one 32-wide c-slice, written to Vp[cs]
        int bb2 = b - 64;
        int orig = bb2 >> 3, cs = bb2 & 7;
        int og = (orig & 63) * 4, h = orig >> 6;
        const float* w2r = W2 + (size_t)og * 256;
        const float* wgp = Wg + ((size_t)h * 256) * 256 + tid;
        float a0 = 0.f, a1 = 0.f, a2 = 0.f, a3 = 0.f;
        int cb = cs * 32;
        #pragma unroll 4
        for (int c = cb; c < cb + 32; ++c) {
            float wv = wgp[(size_t)c * 256];
            a0 = fmaf(w2r[c],       wv, a0);
            a1 = fmaf(w2r[256 + c], wv, a1);
            a2 = fmaf(w2r[512 + c], wv, a2);
            a3 = fmaf(w2r[768 + c], wv, a3);
        }
        size_t base = (size_t)cs * PSZ + (size_t)og * 1024 + h * 256 + tid;
        Vp[base]        = a0;
        Vp[base + 1024] = a1;
        Vp[base + 2048] = a2;
        Vp[base + 3072] = a3;
        return;
    }
    {
        // padded-CSR scatter
        int e = (b - 2112) * 256 + tid;
        int src, dst;
        if (e < E_EDGES) { src = ei[e]; dst = ei[E_EDGES + e]; }
        else             { src = dst = e - E_EDGES; }
        int pos = atomicAdd(cnt + dst, 1);
        csr[(size_t)dst * MAXDEG + pos] = src;
    }
}

// ==== K2: 0..2047 Wz split-8 -> Wzp (plain stores; V summed from Vp via LDS) |
//          2048..2111 u2/c0 ====
__global__ __launch_bounds__(256) void prep2(
    const float* __restrict__ t, const float* __restrict__ W1,
    const float* __restrict__ b1, const float* __restrict__ Vp,
    const float* __restrict__ W2, const float* __restrict__ bg,
    const float* __restrict__ b2, float* __restrict__ u2,
    float* __restrict__ c0, float* __restrict__ Wzp,
    float* __restrict__ bias_z)
{
    __shared__ float red[4][4];
    __shared__ float vsh[4][32];
    int b = blockIdx.x;
    int d = threadIdx.x;

    if (b < 2048) {
        int orig = b >> 3, ks = b & 7;
        int og = (orig & 63) * 4, h = orig >> 6;
        int lane = d & 63, wid = d >> 6;
        int kb = ks * 32;
        size_t vbase = (size_t)og * 1024 + h * 256;

        // cooperative sum of the 8 V-partials for this block's 4x32 slice
        if (d < 128) {
            int j = d >> 5, kk = d & 31;
            float s = 0.f;
            #pragma unroll
            for (int cs = 0; cs < 8; ++cs)
                s += Vp[(size_t)cs * PSZ + vbase + (size_t)j * 1024 + kb + kk];
            vsh[j][kk] = s;
        }
        __syncthreads();

        float a0 = 0.f, a1 = 0.f, a2 = 0.f, a3 = 0.f;
        #pragma unroll 4
        for (int k = 0; k < 32; ++k) {
            float w1v = W1[(size_t)(kb + k) * 256 + d];
            a0 = fmaf(vsh[0][k], w1v, a0);
            a1 = fmaf(vsh[1][k], w1v, a1);
            a2 = fmaf(vsh[2][k], w1v, a2);
            a3 = fmaf(vsh[3][k], w1v, a3);
        }
        size_t base = (size_t)ks * PSZ + vbase + d;
        Wzp[base]        = a0;
        Wzp[base + 1024] = a1;
        Wzp[base + 2048] = a2;
        Wzp[base + 3072] = a3;

        if (ks == 0) {
            float b1v = b1[d];
            #pragma unroll
            for (int j = 0; j < 4; ++j) {
                float vsum = 0.f;
                #pragma unroll
                for (int cs = 0; cs < 8; ++cs)
                    vsum += Vp[(size_t)cs * PSZ + vbase + (size_t)j * 1024 + d];
                float p = vsum * b1v;
                for (int s = 32; s; s >>= 1) p += __shfl_xor(p, s);
                if (lane == 0) red[j][wid] = p;
            }
            __syncthreads();
            if (d < 4) {
                float s = red[d][0] + red[d][1] + red[d][2] + red[d][3];
                atomicAdd(&bias_z[og + d], 0.25f * s);
            }
            if (h == 0) {
                __syncthreads();
                float bgv = bg[d];
                #pragma unroll
                for (int j = 0; j < 4; ++j) {
                    float q = W2[(size_t)(og + j) * 256 + d] * bgv;
                    for (int s = 32; s; s >>= 1) q += __shfl_xor(q, s);
                    if (lane == 0) red[j][wid] = q;
                }
                __syncthreads();
                if (d < 4) {
                    float s = red[d][0] + red[d][1] + red[d][2] + red[d][3];
                    atomicAdd(&bias_z[og + d], s + b2[og + d]);
                }
            }
        }
        return;
    }
    {
        int bb = b - 2048;
        int v = bb >> 3, sl = bb & 7;
        const float* tv = t + v * 256;
        float acc = 0.f;
        #pragma unroll
        for (int j = 0; j < 32; ++j) {
            int k = sl * 32 + j;
            acc = fmaf(tv[k], W1[(size_t)k * 256 + d], acc);
        }
        atomicAdd(&u2[v * 256 + d], acc);
        if (d < 32) {
            float p = tv[sl * 32 + d] * b1[sl * 32 + d];
            for (int s = 16; s; s >>= 1) p += __shfl_xor(p, s);
            if (d == 0) atomicAdd(&c0[v], p);
        }
    }
}

// ==== K3: 0..4095 logits | 4096..4351 Wzp sum + f32->bf16 cvt ====
__global__ __launch_bounds__(256) void logits_cvt(
    const __bf16* __restrict__ x_ln, const float* __restrict__ u2,
    const float* __restrict__ c0, float* __restrict__ a_src,
    float* __restrict__ a_dst, const float* __restrict__ Wzp,
    __bf16* __restrict__ Wz)
{
    int b = blockIdx.x;
    int tid = threadIdx.x;
    if (b >= 4096) {
        int idx = (b - 4096) * 256 + tid;    // 65536 float4 groups
        float4 v = make_float4(0.f, 0.f, 0.f, 0.f);
        #pragma unroll
        for (int p = 0; p < 8; ++p) {
            float4 t4 = ((const float4*)(Wzp + (size_t)p * PSZ))[idx];
            v.x += t4.x; v.y += t4.y; v.z += t4.z; v.w += t4.w;
        }
        bf16x4 o;
        o[0] = f2bf(v.x); o[1] = f2bf(v.y); o[2] = f2bf(v.z); o[3] = f2bf(v.w);
        *(bf16x4*)(Wz + (size_t)idx * 4) = o;
        return;
    }
    __shared__ float u2s[8][256];
    __shared__ float c0s[8];
    #pragma unroll
    for (int k = 0; k < 8; ++k) u2s[k][tid] = u2[k * 256 + tid];
    if (tid < 8) c0s[tid] = c0[tid];
    __syncthreads();

    int wave = tid >> 6, lane = tid & 63;
    int n = b * 4 + wave;
    int v = lane >> 3, p = lane & 7;
    const __bf16* xp = x_ln + (size_t)n * D_MODEL + p * 32;
    const float*  up = &u2s[v][p * 32];
    float acc = 0.f;
    #pragma unroll
    for (int ti = 0; ti < 4; ++ti) {
        bf16x8 x = *(const bf16x8*)(xp + ti * 8);
        #pragma unroll
        for (int j = 0; j < 8; ++j)
            acc = fmaf(bf2f(x[j]), up[ti * 8 + j], acc);
    }
    acc += __shfl_xor(acc, 1);
    acc += __shfl_xor(acc, 2);
    acc += __shfl_xor(acc, 4);
    if (p == 0) {
        float o = acc + c0s[v];
        if (v < 4) a_src[n * H_HEADS + v] = o;
        else       a_dst[n * H_HEADS + (v - 4)] = o;
    }
}

// ==== K4: fused softmax + aggregation (padded CSR, lane-shfl, unroll-4) ====
__global__ __launch_bounds__(256) void gat_fused(
    const __bf16* __restrict__ x_ln, const float* __restrict__ a_src,
    const float* __restrict__ a_dst, const int* __restrict__ cnt,
    const int* __restrict__ csr, __bf16* __restrict__ agg)
{
    int wave = threadIdx.x >> 6, lane = threadIdx.x & 63;
    int i = blockIdx.x * 4 + wave;
    int deg = cnt[i];
    int sidx = csr[(size_t)i * MAXDEG + lane];   // coalesced; garbage past deg
    float4 ad = *(const float4*)(a_dst + i * H_HEADS);

    float acc[4][4] = {};
    float sm0 = 0.f, sm1 = 0.f, sm2 = 0.f, sm3 = 0.f;

    int e = 0;
    for (; e + 4 <= deg; e += 4) {
        int s0 = __shfl(sidx, e);
        int s1 = __shfl(sidx, e + 1);
        int s2 = __shfl(sidx, e + 2);
        int s3 = __shfl(sidx, e + 3);
        float4 A0 = *(const float4*)(a_src + s0 * H_HEADS);
        float4 A1 = *(const float4*)(a_src + s1 * H_HEADS);
        float4 A2 = *(const float4*)(a_src + s2 * H_HEADS);
        float4 A3 = *(const float4*)(a_src + s3 * H_HEADS);
        bf16x4 X0 = *(const bf16x4*)(x_ln + (size_t)s0 * D_MODEL + lane * 4);
        bf16x4 X1 = *(const bf16x4*)(x_ln + (size_t)s1 * D_MODEL + lane * 4);
        bf16x4 X2 = *(const bf16x4*)(x_ln + (size_t)s2 * D_MODEL + lane * 4);
        bf16x4 X3 = *(const bf16x4*)(x_ln + (size_t)s3 * D_MODEL + lane * 4);

        float l[4][4] = {
            {A0.x + ad.x, A0.y + ad.y, A0.z + ad.z, A0.w + ad.w},
            {A1.x + ad.x, A1.y + ad.y, A1.z + ad.z, A1.w + ad.w},
            {A2.x + ad.x, A2.y + ad.y, A2.z + ad.z, A2.w + ad.w},
            {A3.x + ad.x, A3.y + ad.y, A3.z + ad.z, A3.w + ad.w}};
        float wgt[4][4];
        #pragma unroll
        for (int q = 0; q < 4; ++q)
            #pragma unroll
            for (int h = 0; h < 4; ++h) {
                float lv = l[q][h];
                lv = (lv > 0.f) ? lv : 0.2f * lv;
                wgt[q][h] = __expf(lv);
            }
        sm0 += wgt[0][0] + wgt[1][0] + wgt[2][0] + wgt[3][0];
        sm1 += wgt[0][1] + wgt[1][1] + wgt[2][1] + wgt[3][1];
        sm2 += wgt[0][2] + wgt[1][2] + wgt[2][2] + wgt[3][2];
        sm3 += wgt[0][3] + wgt[1][3] + wgt[2][3] + wgt[3][3];
        #pragma unroll
        for (int j = 0; j < 4; ++j) {
            float x0 = bf2f(X0[j]), x1 = bf2f(X1[j]);
            float x2 = bf2f(X2[j]), x3 = bf2f(X3[j]);
            #pragma unroll
            for (int h = 0; h < 4; ++h) {
                float a = acc[h][j];
                a = fmaf(wgt[0][h], x0, a);
                a = fmaf(wgt[1][h], x1, a);
                a = fmaf(wgt[2][h], x2, a);
                a = fmaf(wgt[3][h], x3, a);
                acc[h][j] = a;
            }
        }
    }
    for (; e < deg; ++e) {
        int s = __shfl(sidx, e);
        float4 as = *(const float4*)(a_src + s * H_HEADS);
        bf16x4 x = *(const bf16x4*)(x_ln + (size_t)s * D_MODEL + lane * 4);
        float l0 = as.x + ad.x, l1 = as.y + ad.y,
              l2 = as.z + ad.z, l3 = as.w + ad.w;
        l0 = (l0 > 0.f) ? l0 : 0.2f * l0;
        l1 = (l1 > 0.f) ? l1 : 0.2f * l1;
        l2 = (l2 > 0.f) ? l2 : 0.2f * l2;
        l3 = (l3 > 0.f) ? l3 : 0.2f * l3;
        float w0 = __expf(l0), w1 = __expf(l1);
        float w2 = __expf(l2), w3 = __expf(l3);
        sm0 += w0; sm1 += w1; sm2 += w2; sm3 += w3;
        #pragma unroll
        for (int j = 0; j < 4; ++j) {
            float xv = bf2f(x[j]);
            acc[0][j] = fmaf(w0, xv, acc[0][j]);
            acc[1][j] = fmaf(w1, xv, acc[1][j]);
            acc[2][j] = fmaf(w2, xv, acc[2][j]);
            acc[3][j] = fmaf(w3, xv, acc[3][j]);
        }
    }
    float sc[4] = {0.25f / sm0, 0.25f / sm1, 0.25f / sm2, 0.25f / sm3};
    #pragma unroll
    for (int h = 0; h < 4; ++h) {
        bf16x4 o;
        #pragma unroll
        for (int j = 0; j < 4; ++j) o[j] = f2bf(acc[h][j] * sc[h]);
        *(bf16x4*)(agg + (size_t)i * HC + h * 256 + lane * 4) = o;
    }
}

// -------- K5: skinny bf16 GEMM, 512 threads / 8 waves per block --------
// One block per 64-row A-panel (A fetched once); 8 waves give 8 waves/CU
// (2/SIMD) vs 4 before — halves the exposure of the per-stage barrier drains.
// Each wave owns a 64x32 quadrant (4x2 frags); BK=64 reg double-buffer.
#define APAD 72

__global__ __launch_bounds__(512) void gemm_skinny(
    const __bf16* __restrict__ A, const __bf16* __restrict__ B,
    const float* __restrict__ bias, const float* __restrict__ resid,
    float* __restrict__ outf, int K)
{
    __shared__ __align__(16) __bf16 As[64 * APAD];
    __shared__ __align__(16) __bf16 Bs[256 * APAD];
    int tid  = threadIdx.x;
    int lane = tid & 63;
    int w    = tid >> 6;          // 0..7
    int quad = lane >> 4;
    int l16  = lane & 15;
    int m0 = blockIdx.x * 64;
    int n0 = w * 32;

    int srow = tid >> 3, sp = tid & 7;   // srow 0..63, sp 0..7
    const __bf16* Ab = A + (size_t)(m0 + srow) * K + sp * 8;
    const __bf16* Bb = B + (size_t)srow * K + sp * 8;
    size_t rstride = (size_t)64 * K;

    f32x4 acc[4][2] = {};

    bf16x8 a0_, b0_[4];
    bf16x8 a1_, b1_[4];

    auto compute = [&]() {
        #pragma unroll
        for (int ks = 0; ks < 2; ++ks) {
            bf16x8 af[4], bfr[2];
            #pragma unroll
            for (int mt = 0; mt < 4; ++mt)
                af[mt] = *(const bf16x8*)(As + (mt * 16 + l16) * APAD
                                          + ks * 32 + quad * 8);
            #pragma unroll
            for (int nt = 0; nt < 2; ++nt)
                bfr[nt] = *(const bf16x8*)(Bs + (n0 + nt * 16 + l16) * APAD
                                           + ks * 32 + quad * 8);
            #pragma unroll
            for (int mt = 0; mt < 4; ++mt)
                #pragma unroll
                for (int nt = 0; nt < 2; ++nt)
                    acc[mt][nt] = __builtin_amdgcn_mfma_f32_16x16x32_bf16(
                        af[mt], bfr[nt], acc[mt][nt], 0, 0, 0);
        }
    };

    // prologue: load kb=0 into buf0
    a0_ = *(const bf16x8*)(Ab);
    #pragma unroll
    for (int t = 0; t < 4; ++t)
        b0_[t] = *(const bf16x8*)(Bb + t * rstride);

    for (int kb = 0; kb < K; kb += 128) {
        // ---- stage A: consume buf0 (=kb), prefetch buf1 (=kb+64) ----
        {
            const __bf16* Ap = Ab + kb + 64;
            const __bf16* Bp = Bb + kb + 64;
            a1_ = *(const bf16x8*)(Ap);
            #pragma unroll
            for (int t = 0; t < 4; ++t)
                b1_[t] = *(const bf16x8*)(Bp + t * rstride);
        }
        __syncthreads();
        *(bf16x8*)(As + srow * APAD + sp * 8) = a0_;
        #pragma unroll
        for (int t = 0; t < 4; ++t)
            *(bf16x8*)(Bs + (srow + t * 64) * APAD + sp * 8) = b0_[t];
        __syncthreads();
        compute();

        // ---- stage B: consume buf1 (=kb+64), prefetch buf0 (=kb+128) ----
        if (kb + 128 < K) {
            const __bf16* Ap = Ab + kb + 128;
            const __bf16* Bp = Bb + kb + 128;
            a0_ = *(const bf16x8*)(Ap);
            #pragma unroll
            for (int t = 0; t < 4; ++t)
                b0_[t] = *(const bf16x8*)(Bp + t * rstride);
        }
        __syncthreads();
        *(bf16x8*)(As + srow * APAD + sp * 8) = a1_;
        #pragma unroll
        for (int t = 0; t < 4; ++t)
            *(bf16x8*)(Bs + (srow + t * 64) * APAD + sp * 8) = b1_[t];
        __syncthreads();
        compute();
    }

    #pragma unroll
    for (int nt = 0; nt < 2; ++nt) {
        int col = n0 + nt * 16 + l16;
        float bv = bias[col];
        #pragma unroll
        for (int mt = 0; mt < 4; ++mt) {
            int row = m0 + mt * 16 + quad * 4;
            #pragma unroll
            for (int r = 0; r < 4; ++r) {
                size_t off = (size_t)(row + r) * C_CH + col;
                outf[off] = acc[mt][nt][r] + bv + resid[off];
            }
        }
    }
}

extern "C" void kernel_launch(void* const* d_in, const int* in_sizes, int n_in,
                              void* d_out, int out_size, void* d_ws, size_t ws_size,
                              hipStream_t stream)
{
    const float* inp      = (const float*)d_in[0];
    const int*   ei       = (const int*)  d_in[1];
    const float* ln_gamma = (const float*)d_in[2];
    const float* ln_beta  = (const float*)d_in[3];
    const float* W1       = (const float*)d_in[4];
    const float* b1       = (const float*)d_in[5];
    const float* W_gat    = (const float*)d_in[6];
    const float* att_src  = (const float*)d_in[7];
    const float* att_dst  = (const float*)d_in[8];
    const float* bias_gat = (const float*)d_in[9];
    const float* W2       = (const float*)d_in[10];
    const float* b2       = (const float*)d_in[11];

    char* ws = (char*)d_ws;
    __bf16* x_ln_bf = (__bf16*)(ws);                         //  8 MB
    __bf16* agg_bf  = (__bf16*)(ws + (8ull  << 20));         // 32 MB
    __bf16* Wz_b    = (__bf16*)(ws + (40ull << 20));         // 512 KB
    float*  a_src_b = (float*)(ws + (41ull << 20));          // 256 KB
    float*  a_dst_b = a_src_b + (size_t)N_NODES * H_HEADS;   // 256 KB
    // ---- zero region start (42 MB) ----
    float*  t_vec   = (float*)(ws + (42ull << 20));          //  8 KB
    float*  u2      = t_vec + 2048;                          //  8 KB
    float*  c0      = u2 + 2048;                             //  32 B
    float*  bias_z  = c0 + 8;                                //  1 KB
    int*    cnt     = (int*)(bias_z + 256);                  // 64 KB
    // ---- zero region end ----
    int*    csr     = (int*)(ws + (45ull << 20));            //  4 MB
    float*  Vp      = (float*)(ws + (49ull << 20));          //  8 MB (8 partials)
    float*  Wzp     = (float*)(ws + (57ull << 20));          //  8 MB (8 partials)

    size_t zbytes = (2048 + 2048 + 8 + 256) * sizeof(float)
                  + N_NODES * sizeof(int);
    hipMemsetAsync(t_vec, 0, zbytes, stream);

    prep1_ln<<<2432 + 4096, 256, 0, stream>>>(W_gat, att_src, att_dst, W2, ei,
                                              inp, ln_gamma, ln_beta,
                                              t_vec, Vp, cnt, csr, x_ln_bf);
    prep2<<<2112, 256, 0, stream>>>(t_vec, W1, b1, Vp, W2, bias_gat, b2,
                                    u2, c0, Wzp, bias_z);
    logits_cvt<<<4096 + 256, 256, 0, stream>>>(x_ln_bf, u2, c0,
                                               a_src_b, a_dst_b, Wzp, Wz_b);
    gat_fused<<<N_NODES / 4, 256, 0, stream>>>(x_ln_bf, a_src_b, a_dst_b,
                                               cnt, csr, agg_bf);
    gemm_skinny<<<N_NODES / 64, 512, 0, stream>>>(agg_bf, Wz_b, bias_z, inp,
                                                  (float*)d_out, HC);
}